// Round 8
// baseline (382.031 us; speedup 1.0000x reference)
//
#include <hip/hip_runtime.h>
#include <hip/hip_cooperative_groups.h>

namespace cg = cooperative_groups;
using u32 = unsigned int;
typedef int v4i __attribute__((ext_vector_type(4)));

// ---------------- workspace layout (bytes) ----------------
constexpr int  N_IMG   = 16;
constexpr int  PADROW  = 4096;          // 64 cols * 64 ch bytes
constexpr int  ROWS_PI = 58;            // 56 real + top/bottom pad rows
// header: bmaxX[256] f32 @0, bmaxW1[16] @256*4, bmaxW2[16] @272*4, o1max[256] @288*4, o2max[256] @544*4
constexpr size_t OFS_WSUM9 = 3328;                    // 9*64 ints
constexpr size_t OFS_STX   = 8192;                    // 4608 ints
constexpr size_t OFS_STQ   = 26624;                   // 4608 ints
constexpr size_t OFS_QX    = 45056;
constexpr size_t SZ_QPAD   = (size_t)(1 + N_IMG * ROWS_PI) * PADROW;  // 3,805,184
constexpr size_t OFS_Q1    = OFS_QX + SZ_QPAD;
constexpr size_t SZ_OF     = (size_t)N_IMG * 56 * 56 * 64 * 4;        // 12,845,056
constexpr size_t OFS_O1    = OFS_Q1 + SZ_QPAD;
constexpr size_t OFS_O2    = OFS_O1 + SZ_OF;
constexpr size_t OFS_QW1   = OFS_O2 + SZ_OF;
constexpr size_t OFS_QW2   = OFS_QW1 + 36864;
constexpr size_t SZ_STG    = (size_t)(3 * 224 * 512 + 6 * 16 * 512) * 4;  // 1,572,864
constexpr size_t OFS_STGX  = OFS_QW2 + 36864;
constexpr size_t OFS_STGQ  = OFS_STGX + SZ_STG;
constexpr size_t OFS_WB1   = OFS_STGQ + SZ_STG;
constexpr size_t OFS_WB2   = OFS_WB1 + 18432;
constexpr size_t WS_NEED   = OFS_WB2 + 18432;
constexpr size_t OUTN      = (size_t)16 * 64 * 56 * 56;               // 3,211,264

// stage offsets (ints)
constexpr int STG_J0 = 0;
constexpr int STG_J3 = 224 * 512;
constexpr int STG_J4 = 2 * 224 * 512;
constexpr int STG_SM = 3 * 224 * 512;   // + idx*8192: j1=0,j2=1,(0,0)=2,(0,55)=3,(55,0)=4,(55,55)=5

// ---------------- stats helpers ----------------
static __device__ __forceinline__ void unpack_acc(u32 v, u32 pk[8]) {
#pragma unroll
    for (int k = 0; k < 8; k++) pk[k] += (v >> k) & 0x01010101u;
}

static __device__ __forceinline__ void tree_stage(u32* red, int* dst, const u32 pk[8], int t) {
#pragma unroll
    for (int k = 0; k < 8; k++) red[k * 256 + t] = pk[k];
    __syncthreads();
    if (t < 128) {
#pragma unroll
        for (int k = 0; k < 8; k++) red[k * 256 + t] += red[k * 256 + t + 128];
    }
    __syncthreads();
    if (t < 64) {
#pragma unroll
        for (int k = 0; k < 8; k++) red[k * 256 + t] += red[k * 256 + t + 64];
    }
    __syncthreads();
    if (t < 32) {
#pragma unroll
        for (int k = 0; k < 8; k++) red[k * 256 + t] += red[k * 256 + t + 32];
    }
    __syncthreads();
#pragma unroll
    for (int p = t; p < 512; p += 256) {
        int ci = p >> 3, k = p & 7, ci4 = ci >> 2, b = ci & 3;
        u32 e = red[k * 256 + ci4], o = red[k * 256 + 16 + ci4];
        dst[p] = (int)((e >> (8 * b)) & 0xFF) + (int)((o >> (8 * b)) & 0xFF);
    }
    __syncthreads();
}

static __device__ __forceinline__ void stage_direct(int* dst, const u32 pk[8], int c4) {
#pragma unroll
    for (int k = 0; k < 8; k++)
#pragma unroll
        for (int b = 0; b < 4; b++)
            dst[(c4 * 4 + b) * 8 + k] = (int)((pk[k] >> (8 * b)) & 0xFF);
}

// block max-reduce of 256 floats already in LDS slot r[t]
static __device__ __forceinline__ float blk_max(float* r, int t, float v) {
    r[t] = v; __syncthreads();
    for (int s = 128; s > 0; s >>= 1) {
        if (t < s) r[t] = fmaxf(r[t], r[t + s]);
        __syncthreads();
    }
    float res = r[0]; __syncthreads();
    return res;
}

// ---------------- conv phase: int8 3x3 MFMA implicit GEMM, multi-tile per block ----------------
template <int SECOND>
static __device__ void conv_phase(u32* smem, int bid, int t,
                                  const char* qin, const char* qw, const int* wsum9,
                                  const char* qid,
                                  const float* g, const float* b, const float* m_, const float* v,
                                  float sIn, float sW, float sx,
                                  float* outp, float* omax) {
    u32* lb = smem;                    // 11520
    u32* lin = smem + 11520;           // 3960
    float* redf = (float*)(smem + 15480);
    int w = t >> 6, lane = t & 63, mm = lane & 15, quad = lane >> 4;
    const uint4* bq4 = (const uint4*)qw;
    for (int j4 = t; j4 < 2304; j4 += 256) {
        int row = j4 >> 2, rem = j4 & 3;
        *(uint4*)&lb[row * 20 + rem * 4] = bq4[j4];
    }
    float alpha[4], beta[4];
    int wofs[4];
#pragma unroll
    for (int nt = 0; nt < 4; nt++) {
        int co = nt * 16 + mm;
        float inv = g[co] * rsqrtf(v[co] + 1e-5f);
        alpha[nt] = sIn * sW * inv;
        beta[nt] = b[co] - m_[co] * inv;
        if (SECOND) {
            int s9 = 0;
#pragma unroll
            for (int kp = 0; kp < 9; kp++) s9 += wsum9[kp * 64 + co];
            wofs[nt] = s9 << 7;
        } else wofs[nt] = 0;
    }
    float lmax = 0.f;
    const uint4* qin4 = (const uint4*)qin;
    for (int tile = bid; tile < 896; tile += 256) {
        int n = tile / 56, y = tile - n * 56;
        __syncthreads();
        for (int g4 = t; g4 < 792; g4 += 256) {
            int ky = g4 / 264, r = g4 - ky * 264;
            *(uint4*)&lin[(ky * 66 + (r >> 2)) * 20 + (r & 3) * 4] =
                qin4[(size_t)(1 + n * ROWS_PI + y + ky) * 256 - 4 + r];
        }
        __syncthreads();
        v4i acc[4] = {{0,0,0,0},{0,0,0,0},{0,0,0,0},{0,0,0,0}};
#pragma unroll
        for (int ky = 0; ky < 3; ky++) {
#pragma unroll
            for (int kx = 0; kx < 3; kx++) {
                int px = w * 16 + mm + kx;
                v4i a = *(const v4i*)&lin[(ky * 66 + px) * 20 + quad * 4];
                int tap = ky * 3 + kx;
#pragma unroll
                for (int nt = 0; nt < 4; nt++) {
                    v4i bf = *(const v4i*)&lb[(tap * 64 + nt * 16 + mm) * 20 + quad * 4];
                    acc[nt] = __builtin_amdgcn_mfma_i32_16x16x64_i8(a, bf, acc[nt], 0, 0, 0);
                }
            }
        }
        size_t rowb = (size_t)(n * 56 + y) * 3584;
        const signed char* idrow = SECOND ?
            (const signed char*)(qid + (size_t)(2 + n * ROWS_PI + y) * PADROW) : nullptr;
#pragma unroll
        for (int nt = 0; nt < 4; nt++) {
            int co = nt * 16 + mm;
#pragma unroll
            for (int r = 0; r < 4; r++) {
                int x = w * 16 + quad * 4 + r;
                if (x < 56) {
                    float o = (float)(acc[nt][r] + wofs[nt]) * alpha[nt] + beta[nt];
                    if (SECOND) o += sx * (float)idrow[x * 64 + co];
                    outp[rowb + x * 64 + co] = o;
                    lmax = fmaxf(lmax, o);
                }
            }
        }
    }
    __syncthreads();
    redf[t] = lmax; __syncthreads();
    for (int s = 128; s > 0; s >>= 1) {
        if (t < s) redf[t] = fmaxf(redf[t], redf[t + s]);
        __syncthreads();
    }
    if (t == 0) omax[bid] = redf[0];
    __syncthreads();
}

// ---------------- the mega kernel ----------------
__global__ __launch_bounds__(256, 1) void k_mega(const float* __restrict__ x,
                                                 const float* __restrict__ w1,
                                                 const float* __restrict__ w2,
                                                 const float* __restrict__ g1, const float* __restrict__ b1,
                                                 const float* __restrict__ m1, const float* __restrict__ v1,
                                                 const float* __restrict__ g2, const float* __restrict__ b2,
                                                 const float* __restrict__ m2, const float* __restrict__ v2,
                                                 char* __restrict__ ws, float* __restrict__ outp) {
    __shared__ __align__(16) u32 smem[15744];   // 62,976 B: max over phases
    int bid = blockIdx.x, t = threadIdx.x;
    cg::grid_group grid = cg::this_grid();

    float* hdr   = (float*)ws;
    float* bmaxX = hdr;           // 256
    float* bmaxW1= hdr + 256;     // 16
    float* bmaxW2= hdr + 272;     // 16
    float* o1max = hdr + 288;     // 256
    float* o2max = hdr + 544;     // 256
    int* wsum9 = (int*)(ws + OFS_WSUM9);
    int* stx   = (int*)(ws + OFS_STX);
    int* stq   = (int*)(ws + OFS_STQ);
    char* qx   = ws + OFS_QX;
    char* q1   = ws + OFS_Q1;
    float* o1  = (float*)(ws + OFS_O1);
    float* o2  = (float*)(ws + OFS_O2);
    char* qw1  = ws + OFS_QW1;
    char* qw2  = ws + OFS_QW2;
    int* stgX  = (int*)(ws + OFS_STGX);
    int* stgQ  = (int*)(ws + OFS_STGQ);
    int* wb1   = (int*)(ws + OFS_WB1);
    int* wb2   = (int*)(ws + OFS_WB2);

    // ================= P1: absmax partials =================
    {
        float m = 0.f;
        const float4* x4 = (const float4*)x;
        for (int i = bid * 256 + t; i < 802816; i += 65536) {
            float4 f = x4[i];
            m = fmaxf(m, fmaxf(fmaxf(fabsf(f.x), fabsf(f.y)), fmaxf(fabsf(f.z), fabsf(f.w))));
        }
        float mx = blk_max((float*)smem, t, m);
        if (t == 0) bmaxX[bid] = mx;
        if (bid < 16 || bid >= 240) {
            const float4* w4 = (const float4*)(bid < 16 ? w1 : w2);
            int b = bid < 16 ? bid : bid - 240;
            float mw = 0.f;
            for (int i = b * 256 + t; i < 9216; i += 4096) {
                float4 f = w4[i];
                mw = fmaxf(mw, fmaxf(fmaxf(fabsf(f.x), fabsf(f.y)), fmaxf(fabsf(f.z), fabsf(f.w))));
            }
            float mr = blk_max((float*)smem, t, mw);
            if (t == 0) { if (bid < 16) bmaxW1[b] = mr; else bmaxW2[b] = mr; }
        }
    }
    grid.sync();

    // ================= P2: quant x + stats | quant w =================
    float sX, sW1s, sW2s;
    {
        float* r = (float*)smem;
        sX   = blk_max(r, t, bmaxX[t]) / 127.f;
        sW1s = blk_max(r, t, bmaxW1[t & 15]) / 127.f;
        sW2s = blk_max(r, t, bmaxW2[t & 15]) / 127.f;
    }
    if (bid < 224) {
        int n = bid / 14, slab = bid - n * 14;
        int c4 = t & 15, xg = t >> 4;
        u32* lq = smem;              // 3584
        u32* red = smem + 3584;      // 2048
        int y0 = slab * 4, bi = bid;
        bool doT = (slab == 0), doB = (slab == 13);
        bool colL = (xg == 0), colR = (xg == 13);
        u32 pk[8]  = {0,0,0,0,0,0,0,0};
        u32 pkE[8] = {0,0,0,0,0,0,0,0};
        u32 pkS[8] = {0,0,0,0,0,0,0,0};
        u32 pkC[8] = {0,0,0,0,0,0,0,0};
        if (xg < 14) {
            int c0 = c4 * 4, xx0 = xg * 4;
            const float* base = x + (size_t)n * 200704 + (size_t)c0 * 3136 + (size_t)y0 * 56 + xx0;
#pragma unroll
            for (int r = 0; r < 4; r++) {
                bool er = (doT && r == 0) || (doB && r == 3);
                float4 f[4];
#pragma unroll
                for (int cc = 0; cc < 4; cc++)
                    f[cc] = *(const float4*)(base + (size_t)cc * 3136 + r * 56);
                int qv[4][4];
#pragma unroll
                for (int cc = 0; cc < 4; cc++) {
                    float vv[4] = {f[cc].x, f[cc].y, f[cc].z, f[cc].w};
#pragma unroll
                    for (int i = 0; i < 4; i++) {
                        float q = rintf(vv[i] / sX);
                        q = fminf(fmaxf(q, -127.f), 127.f);
                        qv[cc][i] = (int)q;
                    }
                }
#pragma unroll
                for (int i = 0; i < 4; i++) {
                    u32 d = ((u32)(unsigned char)(signed char)qv[0][i])
                          | ((u32)(unsigned char)(signed char)qv[1][i] << 8)
                          | ((u32)(unsigned char)(signed char)qv[2][i] << 16)
                          | ((u32)(unsigned char)(signed char)qv[3][i] << 24);
                    lq[r * 896 + (xx0 + i) * 16 + c4] = d;
                    unpack_acc(d, pk);
                    if (er) unpack_acc(d, pkE);
                    if ((colL && i == 0) || (colR && i == 3)) {
                        unpack_acc(d, pkS);
                        if (er) unpack_acc(d, pkC);
                    }
                }
            }
        }
        __syncthreads();
        for (int idx = t; idx < 4096; idx += 256) {
            int r = idx >> 10, jd = idx & 1023;
            u32 val = (jd < 896) ? lq[r * 896 + jd] : 0u;
            ((u32*)qx)[(size_t)(2 + n * ROWS_PI + y0 + r) * 1024 + jd] = val;
        }
        if (doT) {
            u32* row = (u32*)(qx + (size_t)(1 + n * ROWS_PI) * PADROW);
            for (int j = t; j < 1024; j += 256) row[j] = 0u;
            if (n == 0) {
                u32* r0 = (u32*)qx;
                for (int j = t; j < 1024; j += 256) r0[j] = 0u;
            }
        }
        if (doB) {
            u32* row = (u32*)(qx + (size_t)(1 + n * ROWS_PI + 57) * PADROW);
            for (int j = t; j < 1024; j += 256) row[j] = 0u;
        }
        tree_stage(red, stgX + STG_J0 + bi * 512, pk, t);
        if (doT) tree_stage(red, stgX + STG_SM + 0 * 8192 + n * 512, pkE, t);
        if (doB) tree_stage(red, stgX + STG_SM + 1 * 8192 + n * 512, pkE, t);
        if (colL) {
            stage_direct(stgX + STG_J3 + bi * 512, pkS, c4);
            if (doT) stage_direct(stgX + STG_SM + 2 * 8192 + n * 512, pkC, c4);
            if (doB) stage_direct(stgX + STG_SM + 4 * 8192 + n * 512, pkC, c4);
        }
        if (colR) {
            stage_direct(stgX + STG_J4 + bi * 512, pkS, c4);
            if (doT) stage_direct(stgX + STG_SM + 3 * 8192 + n * 512, pkC, c4);
            if (doB) stage_direct(stgX + STG_SM + 5 * 8192 + n * 512, pkC, c4);
        }
    } else if (bid < 242) {
        int u_ = bid - 224, wsel = u_ / 9, kp = u_ - wsel * 9;
        const float* w = wsel ? w2 : w1;
        char* qw = wsel ? qw2 : qw1;
        int* wb  = wsel ? wb2 : wb1;
        float s = wsel ? sW2s : sW1s;
        int co = t & 63, cgp = t >> 6;
        int ci0 = cgp * 16;
        signed char qv[16];
        int qsum = 0;
#pragma unroll
        for (int i = 0; i < 16; i++) {
            int ci = ci0 + i;
            float v = w[((size_t)co * 64 + ci) * 9 + kp];
            float qf = rintf(v / s);
            qf = fminf(fmaxf(qf, -127.f), 127.f);
            int q = (int)qf;
            qv[i] = (signed char)q;
            qsum += q;
        }
        u32 pk4[4];
#pragma unroll
        for (int d = 0; d < 4; d++)
            pk4[d] = ((u32)(unsigned char)qv[d*4]) | ((u32)(unsigned char)qv[d*4+1] << 8)
                   | ((u32)(unsigned char)qv[d*4+2] << 16) | ((u32)(unsigned char)qv[d*4+3] << 24);
        *(uint4*)&qw[(size_t)(kp * 64 + co) * 64 + ci0] = *(uint4*)pk4;
#pragma unroll
        for (int i = 0; i < 16; i++) {
            u32 u = (u32)(unsigned char)qv[i];
#pragma unroll
            for (int k = 0; k < 8; k++) {
                unsigned long long bal = __ballot((u >> k) & 1);
                if (co == 0) wb[((ci0 + i) * 8 + k) * 9 + kp] = __popcll(bal);
            }
        }
        if (wsel == 1) {
            int* wsl = (int*)smem;
            wsl[t] = qsum; __syncthreads();
            if (t < 64) wsum9[kp * 64 + t] = wsl[t] + wsl[t + 64] + wsl[t + 128] + wsl[t + 192];
        }
    }
    grid.sync();

    // ================= P3: conv1 =================
    conv_phase<0>(smem, bid, t, qx, qw1, nullptr, nullptr, g1, b1, m1, v1,
                  sX, sW1s, 0.f, o1, o1max);
    grid.sync();

    // ================= P4: relu-quant o1 -> q1 + stats =================
    float s1;
    { s1 = blk_max((float*)smem, t, o1max[t]) / 255.f; }
    if (bid < 224) {
        int n = bid / 14, slab = bid - n * 14;
        u32* red = smem;
        int y0 = slab * 4, bi = bid;
        bool doT = (slab == 0), doB = (slab == 13);
        u32 pk[8]  = {0,0,0,0,0,0,0,0};
        u32 pkE[8] = {0,0,0,0,0,0,0,0};
        u32 pkL[8] = {0,0,0,0,0,0,0,0};
        u32 pkR[8] = {0,0,0,0,0,0,0,0};
        u32 pkC[8] = {0,0,0,0,0,0,0,0};
        const float4* o4 = (const float4*)(o1 + (size_t)(n * 56 + y0) * 3584);
        u32* qd = (u32*)q1;
#pragma unroll
        for (int m = 0; m < 14; m++) {
            int j = t + 256 * m;
            int r = j / 896;
            int rem = j - r * 896;
            int xxp = rem >> 4;
            float4 f = o4[j];
            float vv[4] = {f.x, f.y, f.z, f.w};
            u32 d = 0;
#pragma unroll
            for (int i = 0; i < 4; i++) {
                float q = fminf(rintf(fmaxf(vv[i], 0.f) / s1), 255.f);
                d |= ((u32)((int)q - 128) & 0xFFu) << (8 * i);
            }
            qd[(size_t)(2 + n * ROWS_PI + y0 + r) * 1024 + rem] = d;
            u32 dx = d ^ 0x80808080u;
            unpack_acc(dx, pk);
            bool er = (doT && r == 0) || (doB && r == 3);
            if (er) unpack_acc(dx, pkE);
            if (xxp == 0) {
                unpack_acc(dx, pkL);
                if (er) unpack_acc(dx, pkC);
            } else if (xxp == 55) {
                unpack_acc(dx, pkR);
                if (er) unpack_acc(dx, pkC);
            }
        }
        for (int idx = t; idx < 512; idx += 256) {
            int r = idx >> 7, jd = 896 + (idx & 127);
            qd[(size_t)(2 + n * ROWS_PI + y0 + r) * 1024 + jd] = 0x80808080u;
        }
        if (doT) {
            u32* row = (u32*)(q1 + (size_t)(1 + n * ROWS_PI) * PADROW);
            for (int j = t; j < 1024; j += 256) row[j] = 0x80808080u;
            if (n == 0) {
                u32* r0 = (u32*)q1;
                for (int j = t; j < 1024; j += 256) r0[j] = 0x80808080u;
            }
        }
        if (doB) {
            u32* row = (u32*)(q1 + (size_t)(1 + n * ROWS_PI + 57) * PADROW);
            for (int j = t; j < 1024; j += 256) row[j] = 0x80808080u;
        }
        tree_stage(red, stgQ + STG_J0 + bi * 512, pk, t);
        tree_stage(red, stgQ + STG_J3 + bi * 512, pkL, t);
        tree_stage(red, stgQ + STG_J4 + bi * 512, pkR, t);
        if (doT) tree_stage(red, stgQ + STG_SM + 0 * 8192 + n * 512, pkE, t);
        if (doB) tree_stage(red, stgQ + STG_SM + 1 * 8192 + n * 512, pkE, t);
        if (doT) {
            if (t < 16) stage_direct(stgQ + STG_SM + 2 * 8192 + n * 512, pkC, t);
            else if (t >= 112 && t < 128) stage_direct(stgQ + STG_SM + 3 * 8192 + n * 512, pkC, t - 112);
        }
        if (doB) {
            if (t >= 128 && t < 144) stage_direct(stgQ + STG_SM + 4 * 8192 + n * 512, pkC, t - 128);
            else if (t >= 240) stage_direct(stgQ + STG_SM + 5 * 8192 + n * 512, pkC, t - 240);
        }
    }
    grid.sync();

    // ================= P5: stats reduce + conv2 =================
    if (bid >= 224 && bid < 242) {
        const int offs[9] = {STG_J0, STG_SM, STG_SM + 8192, STG_J3, STG_J4,
                             STG_SM + 2*8192, STG_SM + 3*8192, STG_SM + 4*8192, STG_SM + 5*8192};
        const int cnts[9] = {224, 16, 16, 224, 224, 16, 16, 16, 16};
        int u_ = bid - 224;
        const int* stage = (u_ < 9) ? stgX : stgQ;
        int j = (u_ < 9) ? u_ : u_ - 9;
        int* st = (u_ < 9) ? stx : stq;
        for (int p = t; p < 512; p += 256) {
            const int* base = stage + offs[j] + p;
            int ssum = 0;
            for (int bb = 0; bb < cnts[j]; bb++) ssum += base[bb * 512];
            st[j * 512 + p] = ssum;
        }
    }
    conv_phase<1>(smem, bid, t, q1, qw2, wsum9, qx, g2, b2, m2, v2,
                  s1, sW2s, sX, o2, o2max);
    grid.sync();

    // ================= P6: final quant + transpose; HM on block 0 =================
    float s2;
    { s2 = blk_max((float*)smem, t, o2max[t]) / 255.f; }
    float* lt = (float*)smem;   // 64*57 floats
    for (int u_ = bid; u_ < 896; u_ += 256) {
        int n = u_ / 56, y = u_ - n * 56;
        const float* orow = o2 + (size_t)(n * 56 + y) * 3584;
        __syncthreads();
        for (int idx = t; idx < 3584; idx += 256) {
            int co = idx & 63, xx = idx >> 6;
            float vv = fmaxf(orow[idx], 0.f);
            float q = fminf(rintf(vv / s2), 255.f);
            lt[co * 57 + xx] = q * s2;
        }
        __syncthreads();
        for (int idx = t; idx < 3584; idx += 256) {
            int co = idx / 56, xx = idx - co * 56;
            outp[(size_t)n * 200704 + (size_t)co * 3136 + y * 56 + xx] = lt[co * 57 + xx];
        }
    }
    if (bid == 0) {
        __syncthreads();
        long long act = 0, en = 0;
        for (int p = t; p < 512; p += 256) {
#pragma unroll
            for (int w = 0; w < 2; w++) {
                const int* st = w ? stq : stx;
                const int* wb = w ? wb2 : wb1;
                long long s[9];
#pragma unroll
                for (int j = 0; j < 9; j++) s[j] = st[j * 512 + p];
                const int* wrow = wb + p * 9;
                int w0 = wrow[0], w1_ = wrow[1], w2_ = wrow[2], w3 = wrow[3], w4 = wrow[4],
                    w5 = wrow[5], w6 = wrow[6], w7 = wrow[7], w8 = wrow[8];
                long long wall = (long long)w0 + w1_ + w2_ + w3 + w4 + w5 + w6 + w7 + w8;
                long long wr0 = (long long)w0 + w1_ + w2_;
                long long wr2 = (long long)w6 + w7 + w8;
                long long wc0 = (long long)w0 + w3 + w6;
                long long wc2 = (long long)w2_ + w5 + w8;
                en += s[0] * wall - s[1] * wr2 - s[2] * wr0 - s[3] * wc2 - s[4] * wc0
                    + s[5] * w8 + s[6] * w6 + s[7] * w2_ + s[8] * w0;
                act += s[0];
            }
        }
        long long* rl = (long long*)smem;
        rl[t] = en; __syncthreads();
        for (int s = 128; s > 0; s >>= 1) { if (t < s) rl[t] += rl[t + s]; __syncthreads(); }
        long long etot = rl[0]; __syncthreads();
        rl[t] = act; __syncthreads();
        for (int s = 128; s > 0; s >>= 1) { if (t < s) rl[t] += rl[t + s]; __syncthreads(); }
        if (t == 0) {
            outp[OUTN]     = (float)rl[0];   // HM_act
            outp[OUTN + 1] = (float)etot;    // HM_energy
        }
    }
}

extern "C" void kernel_launch(void* const* d_in, const int* in_sizes, int n_in,
                              void* d_out, int out_size, void* d_ws, size_t ws_size,
                              hipStream_t stream) {
    if (ws_size < WS_NEED) return;
    const float* x  = (const float*)d_in[0];
    const float* w1 = (const float*)d_in[1];
    const float* w2 = (const float*)d_in[2];
    const float* g1 = (const float*)d_in[3];
    const float* b1 = (const float*)d_in[4];
    const float* m1 = (const float*)d_in[5];
    const float* v1 = (const float*)d_in[6];
    const float* g2 = (const float*)d_in[7];
    const float* b2 = (const float*)d_in[8];
    const float* m2 = (const float*)d_in[9];
    const float* v2 = (const float*)d_in[10];
    char* ws = (char*)d_ws;
    float* outp = (float*)d_out;
    void* args[] = {(void*)&x, (void*)&w1, (void*)&w2,
                    (void*)&g1, (void*)&b1, (void*)&m1, (void*)&v1,
                    (void*)&g2, (void*)&b2, (void*)&m2, (void*)&v2,
                    (void*)&ws, (void*)&outp};
    hipLaunchCooperativeKernel((void*)k_mega, dim3(256), dim3(256), args, 0, stream);
}

// Round 9
// 265.693 us; speedup vs baseline: 1.4379x; 1.4379x over previous
//
#include <hip/hip_runtime.h>

using u32 = unsigned int;
typedef int v4i __attribute__((ext_vector_type(4)));

// ---------------- workspace layout (bytes) ----------------
constexpr int  N_IMG   = 16;
constexpr int  PADROW  = 4096;          // 64 cols * 64 ch bytes
constexpr int  ROWS_PI = 58;            // 56 real + top/bottom pad rows
constexpr size_t OFS_BMX  = 0;          // 1024 f : per-block absmax of x
constexpr size_t OFS_BW1  = 4096;       // 16 f
constexpr size_t OFS_BW2  = 4160;       // 16 f
constexpr size_t OFS_O1M  = 4224;       // 896 f : per-block relu-max of o1
constexpr size_t OFS_O2M  = 7808;       // 896 f
constexpr size_t OFS_WSUM9= 11392;      // 576 i : per-tap per-co weight sums (w2)
constexpr size_t OFS_STX  = 13696;      // 4608 i
constexpr size_t OFS_STQ  = 32128;      // 4608 i
constexpr size_t OFS_WB1  = 50560;      // 4608 i
constexpr size_t OFS_WB2  = 68992;      // 4608 i
constexpr size_t OFS_QX   = 98304;
constexpr size_t SZ_QPAD  = (size_t)(1 + N_IMG * ROWS_PI) * PADROW;   // 3,805,184
constexpr size_t OFS_Q1   = OFS_QX + SZ_QPAD;
constexpr size_t OFS_O1   = OFS_Q1 + SZ_QPAD;
constexpr size_t SZ_OF    = (size_t)N_IMG * 56 * 56 * 64 * 4;         // 12,845,056
constexpr size_t OFS_O2   = OFS_O1 + SZ_OF;
constexpr size_t OFS_QW1  = OFS_O2 + SZ_OF;
constexpr size_t OFS_QW2  = OFS_QW1 + 36864;
// stage: j0/j3/j4 448 blocks x 512 ; 6 small cats 16 x 512
constexpr int STG_J0 = 0;
constexpr int STG_J3 = 448 * 512;
constexpr int STG_J4 = 2 * 448 * 512;
constexpr int STG_SM = 3 * 448 * 512;   // + idx*8192: j1=0,j2=1,(0,0)=2,(0,55)=3,(55,0)=4,(55,55)=5
constexpr int STG_TOT = 3 * 448 * 512 + 6 * 16 * 512;                 // 737,280 ints
constexpr size_t OFS_STGX = OFS_QW2 + 36864;
constexpr size_t OFS_STGQ = OFS_STGX + (size_t)STG_TOT * 4;
constexpr size_t WS_NEED  = OFS_STGQ + (size_t)STG_TOT * 4;           // ~39.4 MB
constexpr size_t OUTN     = (size_t)16 * 64 * 56 * 56;                // 3,211,264

// ---------------- helpers ----------------
static __device__ __forceinline__ void unpack_acc(u32 v, u32 pk[8]) {
#pragma unroll
    for (int k = 0; k < 8; k++) pk[k] += (v >> k) & 0x01010101u;
}

static __device__ __forceinline__ float blk_max(float* r, int t, float v) {
    r[t] = v; __syncthreads();
    for (int s = 128; s > 0; s >>= 1) {
        if (t < s) r[t] = fmaxf(r[t], r[t + s]);
        __syncthreads();
    }
    float res = r[0]; __syncthreads();
    return res;
}

// packed-byte tree reduce over the 16 t>>4 groups; plain stores to a stage slot.
static __device__ __forceinline__ void tree_stage(u32* red, int* dst, const u32 pk[8], int t) {
#pragma unroll
    for (int k = 0; k < 8; k++) red[k * 256 + t] = pk[k];
    __syncthreads();
    if (t < 128) {
#pragma unroll
        for (int k = 0; k < 8; k++) red[k * 256 + t] += red[k * 256 + t + 128];
    }
    __syncthreads();
    if (t < 64) {
#pragma unroll
        for (int k = 0; k < 8; k++) red[k * 256 + t] += red[k * 256 + t + 64];
    }
    __syncthreads();
    if (t < 32) {
#pragma unroll
        for (int k = 0; k < 8; k++) red[k * 256 + t] += red[k * 256 + t + 32];
    }
    __syncthreads();
#pragma unroll
    for (int p = t; p < 512; p += 256) {
        int ci = p >> 3, k = p & 7, ci4 = ci >> 2, b = ci & 3;
        u32 e = red[k * 256 + ci4], o = red[k * 256 + 16 + ci4];
        dst[p] = (int)((e >> (8 * b)) & 0xFF) + (int)((o >> (8 * b)) & 0xFF);
    }
    __syncthreads();
}

static __device__ __forceinline__ void stage_direct(int* dst, const u32 pk[8], int c4) {
#pragma unroll
    for (int k = 0; k < 8; k++)
#pragma unroll
        for (int b = 0; b < 4; b++)
            dst[(c4 * 4 + b) * 8 + k] = (int)((pk[k] >> (8 * b)) & 0xFF);
}

// ---------------- A: absmax partials (no atomics, no init needed) ----------------
__global__ __launch_bounds__(256) void k_absmax(const float* __restrict__ x,
                                                const float* __restrict__ w1,
                                                const float* __restrict__ w2,
                                                char* __restrict__ ws) {
    __shared__ float red[256];
    int bid = blockIdx.x, t = threadIdx.x;
    if (bid < 1024) {
        const float4* x4 = (const float4*)x;
        float m = 0.f;
        for (int i = bid * 256 + t; i < 802816; i += 262144) {
            float4 f = x4[i];
            m = fmaxf(m, fmaxf(fmaxf(fabsf(f.x), fabsf(f.y)), fmaxf(fabsf(f.z), fabsf(f.w))));
        }
        float r0 = blk_max(red, t, m);
        if (t == 0) ((float*)(ws + OFS_BMX))[bid] = r0;
    } else {
        int wsel = bid >= 1040;
        const float4* w4 = (const float4*)(wsel ? w2 : w1);
        int b = bid - (wsel ? 1040 : 1024);
        float m = 0.f;
        for (int i = b * 256 + t; i < 9216; i += 4096) {
            float4 f = w4[i];
            m = fmaxf(m, fmaxf(fmaxf(fabsf(f.x), fabsf(f.y)), fmaxf(fabsf(f.z), fabsf(f.w))));
        }
        float r0 = blk_max(red, t, m);
        if (t == 0) ((float*)(ws + (wsel ? OFS_BW2 : OFS_BW1)))[b] = r0;
    }
}

// ---------------- B: quant x (448 2-row slabs) + quant w (18 blocks) ----------------
__global__ __launch_bounds__(256) void k_quant(const float* __restrict__ x,
                                               const float* __restrict__ w1,
                                               const float* __restrict__ w2,
                                               char* __restrict__ ws) {
    __shared__ __align__(16) u32 smem[3840];   // lq 1792 + red 2048
    int bid = blockIdx.x, t = threadIdx.x;
    float* fr = (float*)smem;
    const float* bmx = (const float*)(ws + OFS_BMX);
    float mx = fmaxf(fmaxf(bmx[t], bmx[t + 256]), fmaxf(bmx[t + 512], bmx[t + 768]));
    float sX  = blk_max(fr, t, mx) / 127.f;
    float sW1 = blk_max(fr, t, t < 16 ? ((const float*)(ws + OFS_BW1))[t] : 0.f) / 127.f;
    float sW2 = blk_max(fr, t, t < 16 ? ((const float*)(ws + OFS_BW2))[t] : 0.f) / 127.f;

    if (bid < 448) {
        int n = bid / 28, slab = bid - n * 28, y0 = slab * 2;
        int c4 = t & 15, xg = t >> 4;
        u32* lq = smem;            // 1792
        u32* red = smem + 1792;    // 2048
        char* qx = ws + OFS_QX;
        int* stgX = (int*)(ws + OFS_STGX);
        bool doT = (slab == 0), doB = (slab == 27);
        bool colL = (xg == 0), colR = (xg == 13);
        u32 pk[8] = {0,0,0,0,0,0,0,0}, pkE[8] = {0,0,0,0,0,0,0,0};
        u32 pkS[8] = {0,0,0,0,0,0,0,0}, pkC[8] = {0,0,0,0,0,0,0,0};
        if (xg < 14) {
            int c0 = c4 * 4, xx0 = xg * 4;
            const float* base = x + (size_t)n * 200704 + (size_t)c0 * 3136 + (size_t)y0 * 56 + xx0;
#pragma unroll
            for (int r = 0; r < 2; r++) {
                bool er = (doT && r == 0) || (doB && r == 1);
                float4 f[4];
#pragma unroll
                for (int cc = 0; cc < 4; cc++)
                    f[cc] = *(const float4*)(base + (size_t)cc * 3136 + r * 56);
                int qv[4][4];
#pragma unroll
                for (int cc = 0; cc < 4; cc++) {
                    float vv[4] = {f[cc].x, f[cc].y, f[cc].z, f[cc].w};
#pragma unroll
                    for (int i = 0; i < 4; i++) {
                        float q = rintf(vv[i] / sX);
                        q = fminf(fmaxf(q, -127.f), 127.f);
                        qv[cc][i] = (int)q;
                    }
                }
#pragma unroll
                for (int i = 0; i < 4; i++) {
                    u32 d = ((u32)(unsigned char)(signed char)qv[0][i])
                          | ((u32)(unsigned char)(signed char)qv[1][i] << 8)
                          | ((u32)(unsigned char)(signed char)qv[2][i] << 16)
                          | ((u32)(unsigned char)(signed char)qv[3][i] << 24);
                    lq[r * 896 + (xx0 + i) * 16 + c4] = d;
                    unpack_acc(d, pk);
                    if (er) unpack_acc(d, pkE);
                    if ((colL && i == 0) || (colR && i == 3)) {
                        unpack_acc(d, pkS);
                        if (er) unpack_acc(d, pkC);
                    }
                }
            }
        }
        __syncthreads();
        for (int idx = t; idx < 2048; idx += 256) {
            int r = idx >> 10, jd = idx & 1023;
            ((u32*)qx)[(size_t)(2 + n * ROWS_PI + y0 + r) * 1024 + jd] =
                (jd < 896) ? lq[r * 896 + jd] : 0u;
        }
        if (doT) {
            u32* row = (u32*)(qx + (size_t)(1 + n * ROWS_PI) * PADROW);
            for (int j = t; j < 1024; j += 256) row[j] = 0u;
            if (n == 0) {
                u32* r0 = (u32*)qx;
                for (int j = t; j < 1024; j += 256) r0[j] = 0u;
            }
        }
        if (doB) {
            u32* row = (u32*)(qx + (size_t)(1 + n * ROWS_PI + 57) * PADROW);
            for (int j = t; j < 1024; j += 256) row[j] = 0u;
        }
        tree_stage(red, stgX + STG_J0 + bid * 512, pk, t);
        if (doT) tree_stage(red, stgX + STG_SM + 0 * 8192 + n * 512, pkE, t);
        if (doB) tree_stage(red, stgX + STG_SM + 1 * 8192 + n * 512, pkE, t);
        if (colL) {
            stage_direct(stgX + STG_J3 + bid * 512, pkS, c4);
            if (doT) stage_direct(stgX + STG_SM + 2 * 8192 + n * 512, pkC, c4);
            if (doB) stage_direct(stgX + STG_SM + 4 * 8192 + n * 512, pkC, c4);
        }
        if (colR) {
            stage_direct(stgX + STG_J4 + bid * 512, pkS, c4);
            if (doT) stage_direct(stgX + STG_SM + 3 * 8192 + n * 512, pkC, c4);
            if (doB) stage_direct(stgX + STG_SM + 5 * 8192 + n * 512, pkC, c4);
        }
    } else {
        int u_ = bid - 448, wsel = u_ / 9, kp = u_ - wsel * 9;
        const float* w = wsel ? w2 : w1;
        char* qw = ws + (wsel ? OFS_QW2 : OFS_QW1);
        int* wb  = (int*)(ws + (wsel ? OFS_WB2 : OFS_WB1));
        float s = wsel ? sW2 : sW1;
        int co = t & 63, cgp = t >> 6;
        int ci0 = cgp * 16;
        signed char qv[16];
        int qsum = 0;
#pragma unroll
        for (int i = 0; i < 16; i++) {
            float v = w[((size_t)co * 64 + ci0 + i) * 9 + kp];
            float qf = rintf(v / s);
            qf = fminf(fmaxf(qf, -127.f), 127.f);
            int q = (int)qf;
            qv[i] = (signed char)q;
            qsum += q;
        }
        u32 pk4[4];
#pragma unroll
        for (int d = 0; d < 4; d++)
            pk4[d] = ((u32)(unsigned char)qv[d*4]) | ((u32)(unsigned char)qv[d*4+1] << 8)
                   | ((u32)(unsigned char)qv[d*4+2] << 16) | ((u32)(unsigned char)qv[d*4+3] << 24);
        *(uint4*)&qw[(size_t)(kp * 64 + co) * 64 + ci0] = *(uint4*)pk4;
#pragma unroll
        for (int i = 0; i < 16; i++) {
            u32 u = (u32)(unsigned char)qv[i];
#pragma unroll
            for (int k = 0; k < 8; k++) {
                unsigned long long bal = __ballot((u >> k) & 1);
                if (co == 0) wb[((ci0 + i) * 8 + k) * 9 + kp] = __popcll(bal);
            }
        }
        if (wsel == 1) {
            int* wsl = (int*)smem;
            wsl[t] = qsum; __syncthreads();
            if (t < 64)
                ((int*)(ws + OFS_WSUM9))[kp * 64 + t] =
                    wsl[t] + wsl[t + 64] + wsl[t + 128] + wsl[t + 192];
        }
    }
}

// ---------------- C/E: int8 conv 3x3 via MFMA implicit GEMM (1 tile/block, 896) ----------------
template <int SECOND>
__global__ __launch_bounds__(256, 2) void k_conv(const float* __restrict__ g,
                                                 const float* __restrict__ b,
                                                 const float* __restrict__ m_,
                                                 const float* __restrict__ v,
                                                 char* __restrict__ ws) {
    __shared__ __align__(16) u32 smem[15744];   // lb 11520 + lin 3960 + redf 256
    int bid = blockIdx.x, t = threadIdx.x;
    float* fr = (float*)smem;
    const float* bmx = (const float*)(ws + OFS_BMX);
    float sX = blk_max(fr, t, fmaxf(fmaxf(bmx[t], bmx[t + 256]),
                                    fmaxf(bmx[t + 512], bmx[t + 768]))) / 127.f;
    float sIn, sW;
    if (SECOND) {
        const float* o1m = (const float*)(ws + OFS_O1M);
        float mm2 = 0.f;
        for (int i = t; i < 896; i += 256) mm2 = fmaxf(mm2, o1m[i]);
        sIn = blk_max(fr, t, mm2) / 255.f;
        sW  = blk_max(fr, t, t < 16 ? ((const float*)(ws + OFS_BW2))[t] : 0.f) / 127.f;
    } else {
        sIn = sX;
        sW  = blk_max(fr, t, t < 16 ? ((const float*)(ws + OFS_BW1))[t] : 0.f) / 127.f;
    }
    if (SECOND && bid < 18) {      // fold stats-reduce into conv2's first blocks
        const int offs[9] = {STG_J0, STG_SM, STG_SM + 8192, STG_J3, STG_J4,
                             STG_SM + 2*8192, STG_SM + 3*8192, STG_SM + 4*8192, STG_SM + 5*8192};
        const int cnts[9] = {448, 16, 16, 448, 448, 16, 16, 16, 16};
        const int* stage = (int*)(ws + (bid < 9 ? OFS_STGX : OFS_STGQ));
        int j = (bid < 9) ? bid : bid - 9;
        int* st = (int*)(ws + (bid < 9 ? OFS_STX : OFS_STQ));
        for (int p = t; p < 512; p += 256) {
            const int* base = stage + offs[j] + p;
            int s = 0;
            for (int bb = 0; bb < cnts[j]; bb++) s += base[bb * 512];
            st[j * 512 + p] = s;
        }
    }
    const char* qin = ws + (SECOND ? OFS_Q1 : OFS_QX);
    const char* qw  = ws + (SECOND ? OFS_QW2 : OFS_QW1);
    const char* qid = ws + OFS_QX;
    float* outp = (float*)(ws + (SECOND ? OFS_O2 : OFS_O1));
    float* omax = (float*)(ws + (SECOND ? OFS_O2M : OFS_O1M));
    const int* wsum9 = (const int*)(ws + OFS_WSUM9);

    u32* lb = smem;                 // [tap*64+co] rows x 20 dw (64B + 16B pad)
    u32* lin = smem + 11520;        // 3 rows x 66 px x 20 dw
    float* redf = (float*)(smem + 15480);
    int w = t >> 6, lane = t & 63, mm = lane & 15, quad = lane >> 4;
    int n = bid / 56, y = bid - n * 56;
    const uint4* bq4 = (const uint4*)qw;
    for (int j4 = t; j4 < 2304; j4 += 256) {
        int row = j4 >> 2, rem = j4 & 3;
        *(uint4*)&lb[row * 20 + rem * 4] = bq4[j4];
    }
    const uint4* qin4 = (const uint4*)qin;
    for (int g4 = t; g4 < 792; g4 += 256) {
        int ky = g4 / 264, r = g4 - ky * 264;
        *(uint4*)&lin[(ky * 66 + (r >> 2)) * 20 + (r & 3) * 4] =
            qin4[(size_t)(1 + n * ROWS_PI + y + ky) * 256 - 4 + r];
    }
    __syncthreads();

    v4i acc[4] = {{0,0,0,0},{0,0,0,0},{0,0,0,0},{0,0,0,0}};
#pragma unroll
    for (int ky = 0; ky < 3; ky++) {
#pragma unroll
        for (int kx = 0; kx < 3; kx++) {
            int px = w * 16 + mm + kx;
            v4i a = *(const v4i*)&lin[(ky * 66 + px) * 20 + quad * 4];
            int tap = ky * 3 + kx;
#pragma unroll
            for (int nt = 0; nt < 4; nt++) {
                v4i bf = *(const v4i*)&lb[(tap * 64 + nt * 16 + mm) * 20 + quad * 4];
                acc[nt] = __builtin_amdgcn_mfma_i32_16x16x64_i8(a, bf, acc[nt], 0, 0, 0);
            }
        }
    }
    float lmax = 0.f;
    size_t rowb = (size_t)(n * 56 + y) * 3584;
    const signed char* idrow = SECOND ?
        (const signed char*)(qid + (size_t)(2 + n * ROWS_PI + y) * PADROW) : nullptr;
#pragma unroll
    for (int nt = 0; nt < 4; nt++) {
        int co = nt * 16 + mm;
        float inv = g[co] * rsqrtf(v[co] + 1e-5f);
        float alpha = sIn * sW * inv;
        float beta = b[co] - m_[co] * inv;
        int wofs = 0;
        if (SECOND) {
            int s9 = 0;
#pragma unroll
            for (int kp = 0; kp < 9; kp++) s9 += wsum9[kp * 64 + co];
            wofs = s9 << 7;
        }
#pragma unroll
        for (int r = 0; r < 4; r++) {
            int x = w * 16 + quad * 4 + r;
            if (x < 56) {
                float o = (float)(acc[nt][r] + wofs) * alpha + beta;
                if (SECOND) o += sX * (float)idrow[x * 64 + co];
                outp[rowb + x * 64 + co] = o;
                lmax = fmaxf(lmax, o);
            }
        }
    }
    redf[t] = lmax; __syncthreads();
    for (int s = 128; s > 0; s >>= 1) {
        if (t < s) redf[t] = fmaxf(redf[t], redf[t + s]);
        __syncthreads();
    }
    if (t == 0) omax[bid] = redf[0];
}

// ---------------- D: relu-quant o1 -> q1-128 padded + stats (448 2-row slabs) ----------------
__global__ __launch_bounds__(256) void k_qr1s(char* __restrict__ ws) {
    __shared__ u32 red[2048];
    int bid = blockIdx.x, t = threadIdx.x;
    float* fr = (float*)red;
    const float* o1m = (const float*)(ws + OFS_O1M);
    float mm2 = 0.f;
    for (int i = t; i < 896; i += 256) mm2 = fmaxf(mm2, o1m[i]);
    float s1 = blk_max(fr, t, mm2) / 255.f;

    int n = bid / 28, slab = bid - n * 28, y0 = slab * 2;
    const float* o1 = (const float*)(ws + OFS_O1);
    char* q1 = ws + OFS_Q1;
    int* stgQ = (int*)(ws + OFS_STGQ);
    bool doT = (slab == 0), doB = (slab == 27);
    u32 pk[8] = {0,0,0,0,0,0,0,0}, pkE[8] = {0,0,0,0,0,0,0,0};
    u32 pkL[8] = {0,0,0,0,0,0,0,0}, pkR[8] = {0,0,0,0,0,0,0,0};
    u32 pkC[8] = {0,0,0,0,0,0,0,0};
    const float4* o4 = (const float4*)(o1 + (size_t)(n * 56 + y0) * 3584);
    u32* qd = (u32*)q1;
#pragma unroll
    for (int m = 0; m < 7; m++) {
        int j = t + 256 * m;
        int r = j / 896, rem = j - r * 896;
        int xxp = rem >> 4;
        float4 f = o4[j];
        float vv[4] = {f.x, f.y, f.z, f.w};
        u32 d = 0;
#pragma unroll
        for (int i = 0; i < 4; i++) {
            float q = fminf(rintf(fmaxf(vv[i], 0.f) / s1), 255.f);
            d |= ((u32)((int)q - 128) & 0xFFu) << (8 * i);
        }
        qd[(size_t)(2 + n * ROWS_PI + y0 + r) * 1024 + rem] = d;
        u32 dx = d ^ 0x80808080u;
        unpack_acc(dx, pk);
        bool er = (doT && r == 0) || (doB && r == 1);
        if (er) unpack_acc(dx, pkE);
        if (xxp == 0) {
            unpack_acc(dx, pkL);
            if (er) unpack_acc(dx, pkC);
        } else if (xxp == 55) {
            unpack_acc(dx, pkR);
            if (er) unpack_acc(dx, pkC);
        }
    }
    if (t < 256) {   // 2 rows x 128 pad dwords
        int r = t >> 7, jd = 896 + (t & 127);
        qd[(size_t)(2 + n * ROWS_PI + y0 + r) * 1024 + jd] = 0x80808080u;
    }
    if (doT) {
        u32* row = (u32*)(q1 + (size_t)(1 + n * ROWS_PI) * PADROW);
        for (int j = t; j < 1024; j += 256) row[j] = 0x80808080u;
        if (n == 0) {
            u32* r0 = (u32*)q1;
            for (int j = t; j < 1024; j += 256) r0[j] = 0x80808080u;
        }
    }
    if (doB) {
        u32* row = (u32*)(q1 + (size_t)(1 + n * ROWS_PI + 57) * PADROW);
        for (int j = t; j < 1024; j += 256) row[j] = 0x80808080u;
    }
    tree_stage(red, stgQ + STG_J0 + bid * 512, pk, t);
    tree_stage(red, stgQ + STG_J3 + bid * 512, pkL, t);
    tree_stage(red, stgQ + STG_J4 + bid * 512, pkR, t);
    if (doT) tree_stage(red, stgQ + STG_SM + 0 * 8192 + n * 512, pkE, t);
    if (doB) tree_stage(red, stgQ + STG_SM + 1 * 8192 + n * 512, pkE, t);
    if (doT) {
        if (t < 16) stage_direct(stgQ + STG_SM + 2 * 8192 + n * 512, pkC, t);
        else if (t >= 112 && t < 128) stage_direct(stgQ + STG_SM + 3 * 8192 + n * 512, pkC, t - 112);
    }
    if (doB) {
        if (t >= 128 && t < 144) stage_direct(stgQ + STG_SM + 4 * 8192 + n * 512, pkC, t - 128);
        else if (t >= 240) stage_direct(stgQ + STG_SM + 5 * 8192 + n * 512, pkC, t - 240);
    }
}

// ---------------- F: final quantize + NHWC->NCHW transpose; HM on block 0 ----------------
__global__ __launch_bounds__(256) void k_final(char* __restrict__ ws,
                                               float* __restrict__ outp) {
    __shared__ float lt[64 * 57];
    int bid = blockIdx.x, t = threadIdx.x;
    const float* o2m = (const float*)(ws + OFS_O2M);
    float mm2 = 0.f;
    for (int i = t; i < 896; i += 256) mm2 = fmaxf(mm2, o2m[i]);
    float s2 = blk_max(lt, t, mm2) / 255.f;

    int n = bid / 56, y = bid - n * 56;
    const float* orow = (const float*)(ws + OFS_O2) + (size_t)(n * 56 + y) * 3584;
    for (int idx = t; idx < 3584; idx += 256) {
        int co = idx & 63, xx = idx >> 6;
        float vv = fmaxf(orow[idx], 0.f);
        float q = fminf(rintf(vv / s2), 255.f);
        lt[co * 57 + xx] = q * s2;
    }
    __syncthreads();
    for (int idx = t; idx < 3584; idx += 256) {
        int co = idx / 56, xx = idx - co * 56;
        outp[(size_t)n * 200704 + (size_t)co * 3136 + y * 56 + xx] = lt[co * 57 + xx];
    }
    if (bid == 0) {
        __syncthreads();
        const int* stx = (const int*)(ws + OFS_STX);
        const int* stq = (const int*)(ws + OFS_STQ);
        const int* wb1 = (const int*)(ws + OFS_WB1);
        const int* wb2 = (const int*)(ws + OFS_WB2);
        long long act = 0, en = 0;
        for (int p = t; p < 512; p += 256) {
#pragma unroll
            for (int w = 0; w < 2; w++) {
                const int* st = w ? stq : stx;
                const int* wb = w ? wb2 : wb1;
                long long s[9];
#pragma unroll
                for (int j = 0; j < 9; j++) s[j] = st[j * 512 + p];
                const int* wrow = wb + p * 9;
                int w0 = wrow[0], w1_ = wrow[1], w2_ = wrow[2], w3 = wrow[3], w4 = wrow[4],
                    w5 = wrow[5], w6 = wrow[6], w7 = wrow[7], w8 = wrow[8];
                long long wall = (long long)w0 + w1_ + w2_ + w3 + w4 + w5 + w6 + w7 + w8;
                long long wr0 = (long long)w0 + w1_ + w2_;
                long long wr2 = (long long)w6 + w7 + w8;
                long long wc0 = (long long)w0 + w3 + w6;
                long long wc2 = (long long)w2_ + w5 + w8;
                en += s[0] * wall - s[1] * wr2 - s[2] * wr0 - s[3] * wc2 - s[4] * wc0
                    + s[5] * w8 + s[6] * w6 + s[7] * w2_ + s[8] * w0;
                act += s[0];
            }
        }
        long long* rl = (long long*)lt;
        rl[t] = en; __syncthreads();
        for (int s = 128; s > 0; s >>= 1) { if (t < s) rl[t] += rl[t + s]; __syncthreads(); }
        long long etot = rl[0]; __syncthreads();
        rl[t] = act; __syncthreads();
        for (int s = 128; s > 0; s >>= 1) { if (t < s) rl[t] += rl[t + s]; __syncthreads(); }
        if (t == 0) {
            outp[OUTN]     = (float)rl[0];   // HM_act
            outp[OUTN + 1] = (float)etot;    // HM_energy
        }
    }
}

extern "C" void kernel_launch(void* const* d_in, const int* in_sizes, int n_in,
                              void* d_out, int out_size, void* d_ws, size_t ws_size,
                              hipStream_t stream) {
    if (ws_size < WS_NEED) return;
    const float* x  = (const float*)d_in[0];
    const float* w1 = (const float*)d_in[1];
    const float* w2 = (const float*)d_in[2];
    const float* g1 = (const float*)d_in[3];
    const float* b1 = (const float*)d_in[4];
    const float* m1 = (const float*)d_in[5];
    const float* v1 = (const float*)d_in[6];
    const float* g2 = (const float*)d_in[7];
    const float* b2 = (const float*)d_in[8];
    const float* m2 = (const float*)d_in[9];
    const float* v2 = (const float*)d_in[10];
    char* ws = (char*)d_ws;
    float* outp = (float*)d_out;

    k_absmax<<<1056, 256, 0, stream>>>(x, w1, w2, ws);
    k_quant<<<466, 256, 0, stream>>>(x, w1, w2, ws);
    k_conv<0><<<896, 256, 0, stream>>>(g1, b1, m1, v1, ws);
    k_qr1s<<<448, 256, 0, stream>>>(ws);
    k_conv<1><<<896, 256, 0, stream>>>(g2, b2, m2, v2, ws);
    k_final<<<896, 256, 0, stream>>>(ws, outp);
}